// Round 4
// baseline (506.575 us; speedup 1.0000x reference)
//
#include <hip/hip_runtime.h>
#include <cstdint>

#define INDIM 1024
#define OUTDIM 1024
#define NNZ 65536
#define M_ROWS 50000

typedef __bf16 bf16x8 __attribute__((ext_vector_type(8)));
typedef float f32x4 __attribute__((ext_vector_type(4)));
typedef unsigned int u32x4 __attribute__((ext_vector_type(4)));

// ---------------- scatter nnz values into dense fp32 W [OUTDIM][INDIM] ----------------
__global__ void scatter_w_kernel(const float* __restrict__ vals,
                                 const int* __restrict__ edge,
                                 float* __restrict__ Wf) {
    int e = blockIdx.x * blockDim.x + threadIdx.x;
    if (e < NNZ) {
        int r = edge[e];        // row  (output dim)
        int c = edge[NNZ + e];  // col  (input dim)
        atomicAdd(&Wf[r * INDIM + c], vals[e]);  // duplicates accumulate (matches .at[].add)
    }
}

// ---------------- fp32 W -> bf16 W (round via +0x8000 truncate) -----------------------
__global__ void cvt_w_kernel(const float* __restrict__ Wf,
                             unsigned short* __restrict__ Wb) {
    int i = blockIdx.x * blockDim.x + threadIdx.x;
    unsigned u = __builtin_bit_cast(unsigned, Wf[i]) + 0x8000u;
    Wb[i] = (unsigned short)(u >> 16);
}

// pack two fp32 -> one u32 of two bf16 (a = low half = lower k). Same +0x8000 rounding
// as cvt_w and the verified Round-1 cvt_x pass -> numerics identical to the passing run.
__device__ __forceinline__ unsigned pack_bf16x2(float a, float b) {
    unsigned ua = __builtin_bit_cast(unsigned, a) + 0x8000u;
    unsigned ub = __builtin_bit_cast(unsigned, b) + 0x8000u;
    return (ua >> 16) | (ub & 0xffff0000u);
}

__device__ __forceinline__ void async_copy16(const void* g, void* l) {
    __builtin_amdgcn_global_load_lds(
        (const __attribute__((address_space(1))) void*)g,
        (__attribute__((address_space(3))) void*)l, 16, 0, 0);
}

// ---------------- GEMM: out = bf16(X_f32) @ Wb^T + bias --------------------------------
// 128x128 tile, BK=32, 4 waves (2x2), 4x4 frags of 16x16x32 per wave.
// Changes vs verified gemm_bb (154 us, MfmaUtil 28%):
//  (1) 2-phase double-buffered LDS (T3-minimum): STAGE(next) issued BEFORE compute(cur);
//      ONE __syncthreads per iter (its vmcnt(0) drains next-tile loads that had the whole
//      compute phase to land). Write-after-read safe: buf^1 was last read before the
//      previous barrier.
//  (2) A staged as raw fp32 (16 KB/tile) via global_load_lds; f32->bf16 pack moved to
//      fragment-read time (LDS->reg, no global latency on critical path). Kills the
//      separate cvt_x pass (~50 us dispatch + 307 MB traffic).
// A swizzle (fp32): 8x16B chunks/row, phys = data ^ (row&7); row stride 128 B ->
//   bank = (phys*4+word)%32; 16 lanes/quad-group -> 8 slots x 2 lanes = 2-way (free).
//   Source perm == read perm (both XOR row&7), LDS dest linear  [rule #21].
// B swizzle unchanged (4 chunks/row, key (row>>1)&3, measured 0 conflicts).
// XCD-aware bid remap: 8 n-blocks of one m-panel share bid%8 -> same XCD L2.
__global__ void __launch_bounds__(256)
gemm_f32a_kernel(const float* __restrict__ X,
                 const unsigned short* __restrict__ Wb,
                 const float* __restrict__ bias,
                 float* __restrict__ out) {
    __shared__ float As[2][128 * 32];          // 2 x 16 KB fp32, swizzled 16B chunks
    __shared__ unsigned short Bs[2][128 * 32]; // 2 x 8 KB bf16, swizzled 16B chunks

    const int t = threadIdx.x;
    const int w = t >> 6;        // wave id 0..3
    const int l = t & 63;        // lane
    const int wr = w >> 1;       // wave row group (0..1) -> 64 rows
    const int wc = w & 1;        // wave col group (0..1) -> 64 cols
    const int quad = l >> 4;     // 0..3 (k-octet index for frag reads)
    const int lr = l & 15;       // 0..15

    // ---- XCD-aware block remap ----
    const int bid = blockIdx.x;  // 0..3127
    int m_t, n_t;
    if (bid < 3072) {
        m_t = ((bid >> 6) << 3) + (bid & 7);  // 0..383
        n_t = (bid >> 3) & 7;
    } else {
        int r = bid - 3072;                   // 0..55
        m_t = 384 + (r >> 3);                 // 384..390
        n_t = r & 7;
    }
    const int m0 = m_t * 128;
    const int n0 = n_t * 128;

    // ---- A staging map: 1024 chunks (128 rows x 8); thread t covers {t, t+256, ...} ----
    // chunk c = i*256 + t: row = i*32 + (t>>3), phys = t&7,
    // pdata = phys ^ (row&7) = (t&7) ^ ((t>>3)&7)   (i*32 == 0 mod 8)
    const int ar0 = t >> 3;
    const int apdata = (t & 7) ^ (ar0 & 7);
    long asrc0, asrc1, asrc2, asrc3;
    {
        int r0 = m0 + ar0;
        int r1 = m0 + ar0 + 32;
        int r2 = m0 + ar0 + 64;
        int r3 = m0 + ar0 + 96;
        if (r0 >= M_ROWS) r0 = M_ROWS - 1;    // clamp tail (results masked at store)
        if (r1 >= M_ROWS) r1 = M_ROWS - 1;
        if (r2 >= M_ROWS) r2 = M_ROWS - 1;
        if (r3 >= M_ROWS) r3 = M_ROWS - 1;
        asrc0 = (long)r0 * INDIM + apdata * 4;
        asrc1 = (long)r1 * INDIM + apdata * 4;
        asrc2 = (long)r2 * INDIM + apdata * 4;
        asrc3 = (long)r3 * INDIM + apdata * 4;
    }

    // ---- B staging map: 512 chunks (128 rows x 4); thread t covers {t, t+256} ----
    int brow0 = t >> 2;
    int bsoff0 = ((t & 3) ^ ((brow0 >> 1) & 3)) * 8;            // shorts
    int brow1 = (256 + t) >> 2;
    int bsoff1 = (((256 + t) & 3) ^ ((brow1 >> 1) & 3)) * 8;    // shorts
    const long bbase0 = (long)(n0 + brow0) * INDIM + bsoff0;
    const long bbase1 = (long)(n0 + brow1) * INDIM + bsoff1;

    // wave-uniform LDS chunk bases (bytes)
    const size_t aw = (size_t)(w * 64) * 16;
    const size_t bw = (size_t)(w * 64) * 16;

    f32x4 acc[4][4];
#pragma unroll
    for (int i = 0; i < 4; i++)
#pragma unroll
        for (int j = 0; j < 4; j++) acc[i][j] = (f32x4)0.0f;

    float biasv[4];
#pragma unroll
    for (int j = 0; j < 4; j++) biasv[j] = bias[n0 + wc * 64 + j * 16 + lr];

    // ---- 2-phase pipeline ----
    // prologue: stage tile 0 into buf 0
    {
        char* a = (char*)&As[0][0];
        char* b = (char*)&Bs[0][0];
        async_copy16(X + asrc0, a + aw);
        async_copy16(X + asrc1, a + 4096 + aw);
        async_copy16(X + asrc2, a + 8192 + aw);
        async_copy16(X + asrc3, a + 12288 + aw);
        async_copy16(Wb + bbase0, b + bw);
        async_copy16(Wb + bbase1, b + 4096 + bw);
    }
    __syncthreads();  // drain prologue stage

    int buf = 0;
    for (int kt = 0; kt < INDIM; kt += 32) {
        // ---- issue next-tile stage FIRST (lands by end-of-iter barrier) ----
        if (kt + 32 < INDIM) {
            char* a = (char*)&As[buf ^ 1][0];
            char* b = (char*)&Bs[buf ^ 1][0];
            const int kn = kt + 32;
            async_copy16(X + asrc0 + kn, a + aw);
            async_copy16(X + asrc1 + kn, a + 4096 + aw);
            async_copy16(X + asrc2 + kn, a + 8192 + aw);
            async_copy16(X + asrc3 + kn, a + 12288 + aw);
            async_copy16(Wb + bbase0 + kn, b + bw);
            async_copy16(Wb + bbase1 + kn, b + 4096 + bw);
        }

        // ---- fragments (A: f32 read + pack; B: bf16 read), then 16 MFMA ----
        const float* As_c = &As[buf][0];
        const unsigned short* Bs_c = &Bs[buf][0];
        bf16x8 af[4], bfr[4];
        const int p0 = (2 * quad) ^ (lr & 7);
#pragma unroll
        for (int i = 0; i < 4; i++) {
            int row = wr * 64 + i * 16 + lr;
            const float* rp = As_c + row * 32;
            f32x4 c0 = *(const f32x4*)(rp + p0 * 4);        // data chunk 2*quad   (k 0..3)
            f32x4 c1 = *(const f32x4*)(rp + (p0 ^ 1) * 4);  // data chunk 2*quad+1 (k 4..7)
            u32x4 u;
            u.x = pack_bf16x2(c0.x, c0.y);
            u.y = pack_bf16x2(c0.z, c0.w);
            u.z = pack_bf16x2(c1.x, c1.y);
            u.w = pack_bf16x2(c1.z, c1.w);
            af[i] = __builtin_bit_cast(bf16x8, u);
        }
#pragma unroll
        for (int j = 0; j < 4; j++) {
            int row = wc * 64 + j * 16 + lr;
            int ph = quad ^ ((row >> 1) & 3);
            bfr[j] = *(const bf16x8*)(Bs_c + row * 32 + ph * 8);
        }
#pragma unroll
        for (int i = 0; i < 4; i++)
#pragma unroll
            for (int j = 0; j < 4; j++)
                acc[i][j] = __builtin_amdgcn_mfma_f32_16x16x32_bf16(af[i], bfr[j], acc[i][j], 0, 0, 0);

        __syncthreads();  // drains this wave's vmcnt (next-tile stage) + protects LDS
        buf ^= 1;
    }

    // ---- epilogue: C/D layout col=lane&15, row=quad*4+reg ----
#pragma unroll
    for (int i = 0; i < 4; i++) {
#pragma unroll
        for (int j = 0; j < 4; j++) {
            int col = n0 + wc * 64 + j * 16 + lr;
#pragma unroll
            for (int r = 0; r < 4; r++) {
                int row = m0 + wr * 64 + i * 16 + quad * 4 + r;
                if (row < M_ROWS) {
                    out[(long)row * OUTDIM + col] = acc[i][j][r] + biasv[j];
                }
            }
        }
    }
}

extern "C" void kernel_launch(void* const* d_in, const int* in_sizes, int n_in,
                              void* d_out, int out_size, void* d_ws, size_t ws_size,
                              hipStream_t stream) {
    const float* x    = (const float*)d_in[0];
    const float* nnzw = (const float*)d_in[1];
    const float* bias = (const float*)d_in[2];
    const int* edge   = (const int*)d_in[3];
    float* out        = (float*)d_out;

    const size_t wf_bytes = (size_t)OUTDIM * INDIM * 4;   // 4 MB
    float* Wf          = (float*)d_ws;
    unsigned short* Wb = (unsigned short*)((char*)d_ws + wf_bytes);  // 2 MB

    // ws is poisoned 0xAA before every launch -> zero W accumulator every call
    hipMemsetAsync(Wf, 0, wf_bytes, stream);

    scatter_w_kernel<<<NNZ / 256, 256, 0, stream>>>(nnzw, edge, Wf);
    cvt_w_kernel<<<(OUTDIM * INDIM) / 256, 256, 0, stream>>>(Wf, Wb);

    // 391 m-tiles x 8 n-tiles = 3128 blocks, 1-D grid for explicit bid remap
    gemm_f32a_kernel<<<dim3(3128), 256, 0, stream>>>(x, Wb, bias, out);
}

// Round 5
// 505.081 us; speedup vs baseline: 1.0030x; 1.0030x over previous
//
#include <hip/hip_runtime.h>
#include <cstdint>

#define INDIM 1024
#define OUTDIM 1024
#define NNZ 65536
#define M_ROWS 50000

typedef __bf16 bf16x8 __attribute__((ext_vector_type(8)));
typedef float f32x4 __attribute__((ext_vector_type(4)));
typedef unsigned int u32x4 __attribute__((ext_vector_type(4)));

// ---------------- scatter nnz values into dense fp32 W [OUTDIM][INDIM] ----------------
__global__ void scatter_w_kernel(const float* __restrict__ vals,
                                 const int* __restrict__ edge,
                                 float* __restrict__ Wf) {
    int e = blockIdx.x * blockDim.x + threadIdx.x;
    if (e < NNZ) {
        int r = edge[e];        // row  (output dim)
        int c = edge[NNZ + e];  // col  (input dim)
        atomicAdd(&Wf[r * INDIM + c], vals[e]);  // duplicates accumulate (matches .at[].add)
    }
}

// ---------------- fp32 W -> bf16 W (round via +0x8000 truncate) -----------------------
__global__ void cvt_w_kernel(const float* __restrict__ Wf,
                             unsigned short* __restrict__ Wb) {
    int i = blockIdx.x * blockDim.x + threadIdx.x;
    unsigned u = __builtin_bit_cast(unsigned, Wf[i]) + 0x8000u;
    Wb[i] = (unsigned short)(u >> 16);
}

// pack two fp32 -> one u32 holding two bf16 (a in low half = lower k index)
__device__ __forceinline__ unsigned pack_bf16x2(float a, float b) {
    unsigned ua = __builtin_bit_cast(unsigned, a) + 0x8000u;
    unsigned ub = __builtin_bit_cast(unsigned, b) + 0x8000u;
    return (ua >> 16) | (ub & 0xffff0000u);
}

// ---------------- fp32 X -> bf16 Xb, vectorized: 8 elems/thread -----------------------
// 50000*1024 = 51.2M elems; 25000 blocks x 256 thr x 8 = exact cover.
__global__ void cvt_x_kernel(const float* __restrict__ X,
                             unsigned short* __restrict__ Xb) {
    long i = ((long)blockIdx.x * blockDim.x + threadIdx.x) * 8;
    f32x4 a = *(const f32x4*)(X + i);
    f32x4 b = *(const f32x4*)(X + i + 4);
    u32x4 p;
    p.x = pack_bf16x2(a.x, a.y);
    p.y = pack_bf16x2(a.z, a.w);
    p.z = pack_bf16x2(b.x, b.y);
    p.w = pack_bf16x2(b.z, b.w);
    *(u32x4*)(Xb + i) = p;
}

__device__ __forceinline__ void async_copy16(const void* g, void* l) {
    __builtin_amdgcn_global_load_lds(
        (const __attribute__((address_space(1))) void*)g,
        (__attribute__((address_space(3))) void*)l, 16, 0, 0);
}

// ---------------- GEMM: out = Xb @ Wb^T + bias (both operands bf16, async-staged) -----
// Verified Round-1 gemm_bb (154 us, 0 bank conflicts) + ONE delta: T3-minimum 2-phase
// double-buffered LDS. stage(k+1) is issued BEFORE compute(k); the single end-of-iter
// __syncthreads (vmcnt(0)+lgkmcnt(0) drain) both lands tile k+1 and protects buffers.
//   WAR-safe: buf^1 was last read before the previous barrier (lgkm drained there).
//   RAW-safe: the end-of-iter vmcnt(0) drain completes tile k+1 before iter k+1 reads it.
// LDS 32 KB total -> up to 5 blocks/CU. Staging 16 KB/iter (bf16 both operands).
// Swizzle: chunk c (16 B) of row r lives at phys chunk c^((r>>1)&3); source-permuted
// global addresses + linear LDS dest [rule #21]; frag reads apply the same XOR (2-way, free).
// XCD-aware bid remap: the 8 n-blocks of one m-panel share bid%8 -> same XCD L2.
__global__ void __launch_bounds__(256)
gemm_bb2_kernel(const unsigned short* __restrict__ Xb,
                const unsigned short* __restrict__ Wb,
                const float* __restrict__ bias,
                float* __restrict__ out) {
    __shared__ unsigned short As[2][128 * 32];  // 2 x 8 KB, swizzled chunks
    __shared__ unsigned short Bs[2][128 * 32];  // 2 x 8 KB, swizzled chunks

    const int t = threadIdx.x;
    const int w = t >> 6;        // wave id 0..3
    const int l = t & 63;        // lane
    const int wr = w >> 1;       // wave row group (0..1) -> 64 rows
    const int wc = w & 1;        // wave col group (0..1) -> 64 cols
    const int quad = l >> 4;     // 0..3  (= data chunk index for frag reads)
    const int lr = l & 15;       // 0..15

    // ---- XCD-aware block remap ----
    const int bid = blockIdx.x;  // 0..3127
    int m_t, n_t;
    if (bid < 3072) {
        m_t = ((bid >> 6) << 3) + (bid & 7);  // 0..383
        n_t = (bid >> 3) & 7;
    } else {
        int r = bid - 3072;                   // 0..55
        m_t = 384 + (r >> 3);                 // 384..390
        n_t = r & 7;
    }
    const int m0 = m_t * 128;
    const int n0 = n_t * 128;

    // ---- staging source permutation (identical for A and B paths) ----
    // chunk c_idx (0..511) lands linearly in LDS; fetch data chunk pdata so that
    // phys == pdata ^ ((row>>1)&3).
    long asrc_[2], bsrc_[2];
#pragma unroll
    for (int i = 0; i < 2; i++) {
        int c_idx = i * 256 + t;             // phys chunk 0..511
        int row = c_idx >> 2;                // tile row 0..127
        int pdata = (c_idx & 3) ^ ((row >> 1) & 3);
        int soff = pdata * 8;                // shorts
        int ar = m0 + row;
        if (ar >= M_ROWS) ar = M_ROWS - 1;   // clamp tail (results masked at store)
        asrc_[i] = (long)ar * INDIM + soff;
        bsrc_[i] = (long)(n0 + row) * INDIM + soff;
    }
    const size_t ldsw = (size_t)(w * 64) * 16;  // wave-uniform chunk base (bytes)

    f32x4 acc[4][4];
#pragma unroll
    for (int i = 0; i < 4; i++)
#pragma unroll
        for (int j = 0; j < 4; j++) acc[i][j] = (f32x4)0.0f;

    float biasv[4];
#pragma unroll
    for (int j = 0; j < 4; j++) biasv[j] = bias[n0 + wc * 64 + j * 16 + lr];

    // ---- prologue: stage tile 0 into buf 0 ----
    {
        char* a = (char*)&As[0][0];
        char* b = (char*)&Bs[0][0];
        async_copy16(Xb + asrc_[0], a + ldsw);
        async_copy16(Xb + asrc_[1], a + 4096 + ldsw);
        async_copy16(Wb + bsrc_[0], b + ldsw);
        async_copy16(Wb + bsrc_[1], b + 4096 + ldsw);
    }
    __syncthreads();

    int buf = 0;
    for (int kt = 0; kt < INDIM; kt += 32) {
        // ---- issue next-tile stage FIRST (lands by the end-of-iter barrier) ----
        if (kt + 32 < INDIM) {
            char* a = (char*)&As[buf ^ 1][0];
            char* b = (char*)&Bs[buf ^ 1][0];
            const int kn = kt + 32;
            async_copy16(Xb + asrc_[0] + kn, a + ldsw);
            async_copy16(Xb + asrc_[1] + kn, a + 4096 + ldsw);
            async_copy16(Wb + bsrc_[0] + kn, b + ldsw);
            async_copy16(Wb + bsrc_[1] + kn, b + 4096 + ldsw);
        }

        // ---- fragments + 16 MFMA (swizzled reads, verified pattern) ----
        const unsigned short* As_c = &As[buf][0];
        const unsigned short* Bs_c = &Bs[buf][0];
        bf16x8 af[4], bfr[4];
#pragma unroll
        for (int i = 0; i < 4; i++) {
            int row = wr * 64 + i * 16 + lr;
            int ph = quad ^ ((row >> 1) & 3);
            af[i] = *(const bf16x8*)(As_c + row * 32 + ph * 8);
        }
#pragma unroll
        for (int j = 0; j < 4; j++) {
            int row = wc * 64 + j * 16 + lr;
            int ph = quad ^ ((row >> 1) & 3);
            bfr[j] = *(const bf16x8*)(Bs_c + row * 32 + ph * 8);
        }
#pragma unroll
        for (int i = 0; i < 4; i++)
#pragma unroll
            for (int j = 0; j < 4; j++)
                acc[i][j] = __builtin_amdgcn_mfma_f32_16x16x32_bf16(af[i], bfr[j], acc[i][j], 0, 0, 0);

        __syncthreads();  // drains vmcnt (next tile landed) + protects LDS
        buf ^= 1;
    }

    // ---- epilogue: C/D layout col=lane&15, row=quad*4+reg ----
#pragma unroll
    for (int i = 0; i < 4; i++) {
#pragma unroll
        for (int j = 0; j < 4; j++) {
            int col = n0 + wc * 64 + j * 16 + lr;
#pragma unroll
            for (int r = 0; r < 4; r++) {
                int row = m0 + wr * 64 + i * 16 + quad * 4 + r;
                if (row < M_ROWS) {
                    out[(long)row * OUTDIM + col] = acc[i][j][r] + biasv[j];
                }
            }
        }
    }
}

extern "C" void kernel_launch(void* const* d_in, const int* in_sizes, int n_in,
                              void* d_out, int out_size, void* d_ws, size_t ws_size,
                              hipStream_t stream) {
    const float* x    = (const float*)d_in[0];
    const float* nnzw = (const float*)d_in[1];
    const float* bias = (const float*)d_in[2];
    const int* edge   = (const int*)d_in[3];
    float* out        = (float*)d_out;

    const size_t wf_bytes = (size_t)OUTDIM * INDIM * 4;   // 4 MB
    const size_t wb_bytes = (size_t)OUTDIM * INDIM * 2;   // 2 MB
    const size_t xb_off   = wf_bytes + wb_bytes;          // 6 MB
    float* Wf          = (float*)d_ws;
    unsigned short* Wb = (unsigned short*)((char*)d_ws + wf_bytes);
    unsigned short* Xb = (unsigned short*)((char*)d_ws + xb_off);  // 102.4 MB

    // ws is poisoned 0xAA before every launch -> zero W accumulator every call
    hipMemsetAsync(Wf, 0, wf_bytes, stream);

    scatter_w_kernel<<<NNZ / 256, 256, 0, stream>>>(nnzw, edge, Wf);
    cvt_w_kernel<<<(OUTDIM * INDIM) / 256, 256, 0, stream>>>(Wf, Wb);
    cvt_x_kernel<<<(M_ROWS * INDIM) / (256 * 8), 256, 0, stream>>>(x, Xb);

    // 391 m-tiles x 8 n-tiles = 3128 blocks, 1-D grid for explicit bid remap
    gemm_bb2_kernel<<<dim3(3128), 256, 0, stream>>>(Xb, Wb, bias, out);
}